// Round 5
// baseline (2034.487 us; speedup 1.0000x reference)
//
#include <hip/hip_runtime.h>
#include <math.h>

#define N_ATOMS 1000000
#define N_EDGES 4000000
#define N_GRAPHS 1024
#define IN_F 64
#define HID 32
#define LN_EPS 1e-5f
#define NB 1024                       // radix buckets (node_id >> 10)
#define PB 512                        // partition blocks
#define CHUNK ((N_EDGES + PB - 1) / PB)   // 7813
#define NBUCK_USED 977                // ceil(1e6 / 1024)
#define MPAD 33                       // LDS m row stride (floats)
#define CONV_LDS_BYTES (NB * MPAD * 4 + NB * 4 + 2 * HID * HID * 4)  // 147456

typedef unsigned int uint;
typedef unsigned short ushort;

__device__ __forceinline__ float elu_f(float x) {
    return x > 0.0f ? x : expm1f(x);
}
__device__ __forceinline__ uint f2bf(float x) {   // fp32 -> bf16 bits, RNE
    uint u = __float_as_uint(x);
    return (u + 0x7fffu + ((u >> 16) & 1u)) >> 16;
}

// ------- phase A: per-block LDS histograms of src/dst buckets (no global atomics) -------
__global__ __launch_bounds__(256) void hist2(const int* __restrict__ src,
                                             const int* __restrict__ dst,
                                             int* __restrict__ Hs,
                                             int* __restrict__ Hd) {
    __shared__ int hs[NB], hd[NB];
    int blk = blockIdx.x, tid = threadIdx.x;
    for (int i = tid; i < NB; i += 256) { hs[i] = 0; hd[i] = 0; }
    __syncthreads();
    int e0 = blk * CHUNK, e1 = min(N_EDGES, e0 + CHUNK);
    for (int e = e0 + tid; e < e1; e += 256) {
        atomicAdd(&hs[src[e] >> 10], 1);
        atomicAdd(&hd[dst[e] >> 10], 1);
    }
    __syncthreads();
    for (int i = tid; i < NB; i += 256) {
        Hs[blk * NB + i] = hs[i];
        Hd[blk * NB + i] = hd[i];
    }
}

// ------- phase B1: exclusive scan down each bucket column (over PB blocks) -------
__global__ __launch_bounds__(256) void col_scan(int* __restrict__ H,
                                                int* __restrict__ btot) {
    __shared__ int lds[256];
    int b = blockIdx.x, tid = threadIdx.x;
    int v0 = H[(2 * tid) * NB + b];
    int v1 = H[(2 * tid + 1) * NB + b];
    lds[tid] = v0 + v1;
    __syncthreads();
    for (int off = 1; off < 256; off <<= 1) {
        int t = (tid >= off) ? lds[tid - off] : 0;
        __syncthreads();
        lds[tid] += t;
        __syncthreads();
    }
    int excl = (tid > 0) ? lds[tid - 1] : 0;
    H[(2 * tid) * NB + b] = excl;
    H[(2 * tid + 1) * NB + b] = excl + v0;
    if (tid == 255) btot[b] = excl + v0 + v1;
}

// ------- phase B2: exclusive scan of bucket totals (block 0: dst, block 1: src) -------
__global__ __launch_bounds__(256) void bucket_scan(const int* __restrict__ btot_d,
                                                   int* __restrict__ bbase_d,
                                                   const int* __restrict__ btot_s,
                                                   int* __restrict__ bbase_s) {
    __shared__ int lds[256];
    const int* in = (blockIdx.x == 0) ? btot_d : btot_s;
    int* out = (blockIdx.x == 0) ? bbase_d : bbase_s;
    int tid = threadIdx.x;
    int v[4]; int s = 0;
#pragma unroll
    for (int q = 0; q < 4; ++q) { v[q] = in[tid * 4 + q]; s += v[q]; }
    lds[tid] = s;
    __syncthreads();
    for (int off = 1; off < 256; off <<= 1) {
        int t = (tid >= off) ? lds[tid - off] : 0;
        __syncthreads();
        lds[tid] += t;
        __syncthreads();
    }
    int run = (tid > 0) ? lds[tid - 1] : 0;
#pragma unroll
    for (int q = 0; q < 4; ++q) { out[tid * 4 + q] = run; run += v[q]; }
    if (tid == 255) out[NB] = run;   // == N_EDGES
}

// ------- phase C: scatter edges into dst-buckets as (dst,src) pairs -------
__global__ __launch_bounds__(256) void scatter_dst(const int* __restrict__ src,
                                                   const int* __restrict__ dst,
                                                   const int* __restrict__ Hd,
                                                   const int* __restrict__ bbase_d,
                                                   int2* __restrict__ pedge) {
    __shared__ int cur[NB];
    int blk = blockIdx.x, tid = threadIdx.x;
    for (int i = tid; i < NB; i += 256) cur[i] = bbase_d[i] + Hd[blk * NB + i];
    __syncthreads();
    int e0 = blk * CHUNK, e1 = min(N_EDGES, e0 + CHUNK);
    for (int e = e0 + tid; e < e1; e += 256) {
        int d = dst[e], s = src[e];
        int pos = atomicAdd(&cur[d >> 10], 1);
        pedge[pos] = make_int2(d, s);
    }
}

// ------- phase C': scatter src values into src-buckets -------
__global__ __launch_bounds__(256) void scatter_src(const int* __restrict__ src,
                                                   const int* __restrict__ Hs,
                                                   const int* __restrict__ bbase_s,
                                                   int* __restrict__ psrc) {
    __shared__ int cur[NB];
    int blk = blockIdx.x, tid = threadIdx.x;
    for (int i = tid; i < NB; i += 256) cur[i] = bbase_s[i] + Hs[blk * NB + i];
    __syncthreads();
    int e0 = blk * CHUNK, e1 = min(N_EDGES, e0 + CHUNK);
    for (int e = e0 + tid; e < e1; e += 256) {
        int s = src[e];
        int pos = atomicAdd(&cur[s >> 10], 1);
        psrc[pos] = s;
    }
}

// ------- per-bucket out-degree norm -------
__global__ __launch_bounds__(256) void bucket_ns(const int* __restrict__ psrc,
                                                 const int* __restrict__ bbase_s,
                                                 float* __restrict__ ns) {
    __shared__ int deg[NB];
    int b = blockIdx.x, tid = threadIdx.x;
    int nbase = b << 10;
    if (nbase >= N_ATOMS) return;
    int ebase = bbase_s[b], eend = bbase_s[b + 1];
    for (int i = tid; i < NB; i += 256) deg[i] = 0;
    __syncthreads();
    for (int i = ebase + tid; i < eend; i += 256)
        atomicAdd(&deg[psrc[i] & (NB - 1)], 1);
    __syncthreads();
    for (int l = tid; l < NB; l += 256) {
        int node = nbase + l;
        if (node < N_ATOMS) {
            int c = deg[l];
            ns[node] = c > 0 ? rsqrtf((float)c) : 0.0f;
        }
    }
}

// ------- input MLP: Linear(64->32) + LN + ELU, output prescaled by ns -> bf16 -------
__global__ __launch_bounds__(256) void input_mlp(const float* __restrict__ feats,
                                                 const float* __restrict__ w0,
                                                 const float* __restrict__ b0,
                                                 const float* __restrict__ g0,
                                                 const float* __restrict__ be0,
                                                 const float* __restrict__ ns,
                                                 ushort* __restrict__ hs) {
    __shared__ float sf[256 * 65];
    __shared__ float sw[IN_F * HID];
    int base = blockIdx.x * 256;
    int tid = threadIdx.x;

    for (int i = tid; i < IN_F * HID; i += 256) sw[i] = w0[i];

    int nrows = min(256, N_ATOMS - base);
    for (int i = tid; i < nrows * IN_F; i += 256) {
        int r = i >> 6, c = i & 63;
        sf[r * 65 + c] = feats[(size_t)base * IN_F + i];
    }
    __syncthreads();
    if (tid >= nrows) return;

    float acc[HID];
#pragma unroll
    for (int j = 0; j < HID; ++j) acc[j] = b0[j];

    const float* frow = &sf[tid * 65];
#pragma unroll 4
    for (int k = 0; k < IN_F; ++k) {
        float f = frow[k];
#pragma unroll
        for (int j = 0; j < HID; ++j) acc[j] += f * sw[k * HID + j];
    }

    float mu = 0.0f;
#pragma unroll
    for (int j = 0; j < HID; ++j) mu += acc[j];
    mu *= (1.0f / HID);
    float var = 0.0f;
#pragma unroll
    for (int j = 0; j < HID; ++j) { float d = acc[j] - mu; var += d * d; }
    var *= (1.0f / HID);
    float rs = rsqrtf(var + LN_EPS);

    float os = ns[base + tid];
#pragma unroll
    for (int j = 0; j < HID; ++j)
        acc[j] = elu_f((acc[j] - mu) * rs * g0[j] + be0[j]) * os;

    uint words[HID / 2];
#pragma unroll
    for (int q = 0; q < HID / 2; ++q)
        words[q] = f2bf(acc[2 * q]) | (f2bf(acc[2 * q + 1]) << 16);
    uint4* hv = (uint4*)&hs[(size_t)(base + tid) * HID];
#pragma unroll
    for (int q = 0; q < 4; ++q)
        hv[q] = make_uint4(words[4 * q], words[4 * q + 1], words[4 * q + 2], words[4 * q + 3]);
}

// ---- fused GraphConv + node MLP, edge-parallel with LDS accumulation ----
// Block b owns dst-bucket b (1024 nodes). Phase 1: edge-parallel gather of
// h[src] (bf16) accumulated into LDS m[1024][33] fp32 via ds_add, plus LDS
// in-degree count. Phase 2: per-node nd*m @ wc -> ELU -> @ w -> LN -> ELU
// (optionally * ns) -> bf16 write.
__global__ __launch_bounds__(512) void conv_lds(const ushort* __restrict__ hin,
                                                const int2* __restrict__ pedge,
                                                const int* __restrict__ bbase_d,
                                                const float* __restrict__ wc,
                                                const float* __restrict__ bc,
                                                const float* __restrict__ w,
                                                const float* __restrict__ b,
                                                const float* __restrict__ g,
                                                const float* __restrict__ be,
                                                const float* __restrict__ ns_out,
                                                ushort* __restrict__ hout) {
    extern __shared__ char smem[];
    float* sm  = (float*)smem;                         // [1024][33]
    int* sdeg  = (int*)(smem + NB * MPAD * 4);         // [1024]
    float* swc = (float*)(smem + NB * MPAD * 4 + NB * 4);          // [32*32]
    float* sww = swc + HID * HID;                                  // [32*32]

    int bkt = blockIdx.x, tid = threadIdx.x;
    int nbase = bkt << 10;
    int ebase = bbase_d[bkt], eend = bbase_d[bkt + 1];

    for (int i = tid; i < NB * MPAD; i += 512) sm[i] = 0.0f;
    for (int i = tid; i < NB; i += 512) sdeg[i] = 0;
    for (int i = tid; i < HID * HID; i += 512) { swc[i] = wc[i]; sww[i] = w[i]; }
    __syncthreads();

    // ---- phase 1: edge-parallel, 2 edges in flight per lane ----
    int i0 = ebase + tid;
    for (; i0 + 512 < eend; i0 += 1024) {
        int2 ea = pedge[i0];
        int2 eb = pedge[i0 + 512];
        const uint4* ra = (const uint4*)(hin + (size_t)ea.y * HID);
        const uint4* rb = (const uint4*)(hin + (size_t)eb.y * HID);
        uint4 a0 = ra[0], a1 = ra[1], a2 = ra[2], a3 = ra[3];
        uint4 b0 = rb[0], b1 = rb[1], b2 = rb[2], b3 = rb[3];
        int la = ea.x & (NB - 1), lb = eb.x & (NB - 1);
        atomicAdd(&sdeg[la], 1);
        atomicAdd(&sdeg[lb], 1);
        float* ma = &sm[la * MPAD];
        float* mb = &sm[lb * MPAD];
        uint va[16] = {a0.x, a0.y, a0.z, a0.w, a1.x, a1.y, a1.z, a1.w,
                       a2.x, a2.y, a2.z, a2.w, a3.x, a3.y, a3.z, a3.w};
        uint vb[16] = {b0.x, b0.y, b0.z, b0.w, b1.x, b1.y, b1.z, b1.w,
                       b2.x, b2.y, b2.z, b2.w, b3.x, b3.y, b3.z, b3.w};
#pragma unroll
        for (int r = 0; r < 16; ++r) {
            atomicAdd(ma + 2 * r,     __uint_as_float(va[r] << 16));
            atomicAdd(ma + 2 * r + 1, __uint_as_float(va[r] & 0xffff0000u));
        }
#pragma unroll
        for (int r = 0; r < 16; ++r) {
            atomicAdd(mb + 2 * r,     __uint_as_float(vb[r] << 16));
            atomicAdd(mb + 2 * r + 1, __uint_as_float(vb[r] & 0xffff0000u));
        }
    }
    if (i0 < eend) {
        int2 ea = pedge[i0];
        const uint4* ra = (const uint4*)(hin + (size_t)ea.y * HID);
        uint4 a0 = ra[0], a1 = ra[1], a2 = ra[2], a3 = ra[3];
        int la = ea.x & (NB - 1);
        atomicAdd(&sdeg[la], 1);
        float* ma = &sm[la * MPAD];
        uint va[16] = {a0.x, a0.y, a0.z, a0.w, a1.x, a1.y, a1.z, a1.w,
                       a2.x, a2.y, a2.z, a2.w, a3.x, a3.y, a3.z, a3.w};
#pragma unroll
        for (int r = 0; r < 16; ++r) {
            atomicAdd(ma + 2 * r,     __uint_as_float(va[r] << 16));
            atomicAdd(ma + 2 * r + 1, __uint_as_float(va[r] & 0xffff0000u));
        }
    }
    __syncthreads();

    // ---- phase 2: node-parallel (2 nodes per thread) ----
#pragma unroll
    for (int half = 0; half < 2; ++half) {
        int l = tid + half * 512;
        int node = nbase + l;
        if (node >= N_ATOMS) continue;

        int dg = sdeg[l];
        float scale = dg > 0 ? rsqrtf((float)dg) : 0.0f;
        const float* mr = &sm[l * MPAD];

        float t1[HID];
#pragma unroll
        for (int j = 0; j < HID; ++j) t1[j] = bc[j];
#pragma unroll 4
        for (int k = 0; k < HID; ++k) {
            float f = mr[k] * scale;
#pragma unroll
            for (int j = 0; j < HID; ++j) t1[j] += f * swc[k * HID + j];
        }
#pragma unroll
        for (int j = 0; j < HID; ++j) t1[j] = elu_f(t1[j]);

        float t2[HID];
#pragma unroll
        for (int j = 0; j < HID; ++j) t2[j] = b[j];
#pragma unroll 4
        for (int k = 0; k < HID; ++k) {
            float f = t1[k];
#pragma unroll
            for (int j = 0; j < HID; ++j) t2[j] += f * sww[k * HID + j];
        }

        float mu = 0.0f;
#pragma unroll
        for (int j = 0; j < HID; ++j) mu += t2[j];
        mu *= (1.0f / HID);
        float var = 0.0f;
#pragma unroll
        for (int j = 0; j < HID; ++j) { float d = t2[j] - mu; var += d * d; }
        var *= (1.0f / HID);
        float rs = rsqrtf(var + LN_EPS);

        float os = ns_out ? ns_out[node] : 1.0f;
#pragma unroll
        for (int j = 0; j < HID; ++j)
            t2[j] = elu_f((t2[j] - mu) * rs * g[j] + be[j]) * os;

        uint words[HID / 2];
#pragma unroll
        for (int q = 0; q < HID / 2; ++q)
            words[q] = f2bf(t2[2 * q]) | (f2bf(t2[2 * q + 1]) << 16);
        uint4* hv = (uint4*)&hout[(size_t)node * HID];
#pragma unroll
        for (int q = 0; q < 4; ++q)
            hv[q] = make_uint4(words[4 * q], words[4 * q + 1], words[4 * q + 2], words[4 * q + 3]);
    }
}

// ---------------- output head + per-graph readout (gid sorted) ----------------
__global__ __launch_bounds__(256) void readout(const ushort* __restrict__ h,
                                               const int* __restrict__ gid,
                                               const float* __restrict__ wout,
                                               const float* __restrict__ bout,
                                               float* __restrict__ out) {
    __shared__ float swout[HID];
    __shared__ float buckets[N_GRAPHS];
    __shared__ int s_gf, s_range;
    int base = blockIdx.x * 256;
    int tid = threadIdx.x;
    int nrows = min(256, N_ATOMS - base);

    if (tid < HID) swout[tid] = wout[tid];
    if (tid == 0) {
        int gf = gid[base];
        int gl = gid[base + nrows - 1];
        s_gf = gf;
        s_range = gl - gf + 1;
    }
    __syncthreads();
    int gf = s_gf, range = s_range;
    for (int i = tid; i < range; i += 256) buckets[i] = 0.0f;
    __syncthreads();

    if (tid < nrows) {
        int node = base + tid;
        const uint4* hv = (const uint4*)&h[(size_t)node * HID];
        float acc = bout[0];
#pragma unroll
        for (int q = 0; q < 4; ++q) {
            uint4 u = hv[q];
            uint vv[4] = {u.x, u.y, u.z, u.w};
#pragma unroll
            for (int r = 0; r < 4; ++r) {
                float lo = __uint_as_float(vv[r] << 16);
                float hi = __uint_as_float(vv[r] & 0xffff0000u);
                acc += lo * swout[q * 8 + r * 2] + hi * swout[q * 8 + r * 2 + 1];
            }
        }
        acc = elu_f(acc);
        atomicAdd(&buckets[gid[node] - gf], acc);
    }
    __syncthreads();
    for (int i = tid; i < range; i += 256) {
        float v = buckets[i];
        if (v != 0.0f) atomicAdd(&out[gf + i], v);
    }
}

extern "C" void kernel_launch(void* const* d_in, const int* in_sizes, int n_in,
                              void* d_out, int out_size, void* d_ws, size_t ws_size,
                              hipStream_t stream) {
    const float* feats = (const float*)d_in[0];
    const int* src = (const int*)d_in[1];
    const int* dst = (const int*)d_in[2];
    const int* gid = (const int*)d_in[3];
    const float* w0  = (const float*)d_in[4];
    const float* b0  = (const float*)d_in[5];
    const float* g0  = (const float*)d_in[6];
    const float* be0 = (const float*)d_in[7];
    const float* wc1 = (const float*)d_in[8];
    const float* bc1 = (const float*)d_in[9];
    const float* w1  = (const float*)d_in[10];
    const float* b1  = (const float*)d_in[11];
    const float* g1  = (const float*)d_in[12];
    const float* be1 = (const float*)d_in[13];
    const float* wc2 = (const float*)d_in[14];
    const float* bc2 = (const float*)d_in[15];
    const float* w2  = (const float*)d_in[16];
    const float* b2  = (const float*)d_in[17];
    const float* g2  = (const float*)d_in[18];
    const float* be2 = (const float*)d_in[19];
    const float* wout = (const float*)d_in[20];
    const float* bout = (const float*)d_in[21];
    float* out = (float*)d_out;

    // workspace layout (~184 MB)
    char* ws = (char*)d_ws;
    ushort* h0    = (ushort*)(ws + 0);             // 64,000,000
    ushort* h1    = (ushort*)(ws + 64000000);      // 64,000,000
    int2* pedge   = (int2*)(ws + 128000000);       // 32,000,000
    int* psrc     = (int*)(ws + 160000000);        // 16,000,000
    int* Hd       = (int*)(ws + 176000000);        // 2,097,152
    int* Hs       = (int*)(ws + 178097152);        // 2,097,152
    int* btot_d   = (int*)(ws + 180194304);        // 4,096
    int* btot_s   = (int*)(ws + 180198400);        // 4,096
    int* bbase_d  = (int*)(ws + 180202496);        // 4,352 (NB+1)
    int* bbase_s  = (int*)(ws + 180206848);        // 4,352
    float* ns     = (float*)(ws + 180211200);      // 4,000,000

    hipMemsetAsync(out, 0, (size_t)N_GRAPHS * sizeof(float), stream);

    int nb = (N_ATOMS + 255) / 256;   // 3907

    hist2<<<PB, 256, 0, stream>>>(src, dst, Hs, Hd);
    col_scan<<<NB, 256, 0, stream>>>(Hd, btot_d);
    col_scan<<<NB, 256, 0, stream>>>(Hs, btot_s);
    bucket_scan<<<2, 256, 0, stream>>>(btot_d, bbase_d, btot_s, bbase_s);
    scatter_dst<<<PB, 256, 0, stream>>>(src, dst, Hd, bbase_d, pedge);
    scatter_src<<<PB, 256, 0, stream>>>(src, Hs, bbase_s, psrc);
    bucket_ns<<<NBUCK_USED, 256, 0, stream>>>(psrc, bbase_s, ns);

    input_mlp<<<nb, 256, 0, stream>>>(feats, w0, b0, g0, be0, ns, h0);

    hipFuncSetAttribute(reinterpret_cast<const void*>(conv_lds),
                        hipFuncAttributeMaxDynamicSharedMemorySize, CONV_LDS_BYTES);
    conv_lds<<<NBUCK_USED, 512, CONV_LDS_BYTES, stream>>>(h0, pedge, bbase_d,
                                                          wc1, bc1, w1, b1, g1, be1, ns, h1);
    conv_lds<<<NBUCK_USED, 512, CONV_LDS_BYTES, stream>>>(h1, pedge, bbase_d,
                                                          wc2, bc2, w2, b2, g2, be2, nullptr, h0);

    readout<<<nb, 256, 0, stream>>>(h0, gid, wout, bout, out);
}

// Round 7
// 1398.049 us; speedup vs baseline: 1.4552x; 1.4552x over previous
//
#include <hip/hip_runtime.h>
#include <math.h>

#define N_ATOMS 1000000
#define N_EDGES 4000000
#define N_GRAPHS 1024
#define IN_F 64
#define HID 32
#define LN_EPS 1e-5f
#define NB 1024                       // radix buckets (node_id >> 10)
#define PB 512                        // partition blocks
#define CHUNK ((N_EDGES + PB - 1) / PB)   // 7813
#define NBUCK_USED 977                // ceil(1e6 / 1024)

typedef unsigned int uint;
typedef unsigned short ushort;

__device__ __forceinline__ float elu_f(float x) {
    return x > 0.0f ? x : expm1f(x);
}
__device__ __forceinline__ uint f2bf(float x) {   // fp32 -> bf16 bits, RNE
    uint u = __float_as_uint(x);
    return (u + 0x7fffu + ((u >> 16) & 1u)) >> 16;
}
__device__ __forceinline__ void acc8(float* a, uint4 u) {
    uint v[4] = {u.x, u.y, u.z, u.w};
#pragma unroll
    for (int r = 0; r < 4; ++r) {
        a[2 * r]     += __uint_as_float(v[r] << 16);
        a[2 * r + 1] += __uint_as_float(v[r] & 0xffff0000u);
    }
}

// ------- phase A: per-block LDS histograms of src/dst buckets -------
__global__ __launch_bounds__(256) void hist2(const int* __restrict__ src,
                                             const int* __restrict__ dst,
                                             int* __restrict__ Hs,
                                             int* __restrict__ Hd) {
    __shared__ int hs[NB], hd[NB];
    int blk = blockIdx.x, tid = threadIdx.x;
    for (int i = tid; i < NB; i += 256) { hs[i] = 0; hd[i] = 0; }
    __syncthreads();
    int e0 = blk * CHUNK, e1 = min(N_EDGES, e0 + CHUNK);
    for (int e = e0 + tid; e < e1; e += 256) {
        atomicAdd(&hs[src[e] >> 10], 1);
        atomicAdd(&hd[dst[e] >> 10], 1);
    }
    __syncthreads();
    for (int i = tid; i < NB; i += 256) {
        Hs[blk * NB + i] = hs[i];
        Hd[blk * NB + i] = hd[i];
    }
}

// ------- phase B1: exclusive scan down each bucket column -------
__global__ __launch_bounds__(256) void col_scan(int* __restrict__ H,
                                                int* __restrict__ btot) {
    __shared__ int lds[256];
    int b = blockIdx.x, tid = threadIdx.x;
    int v0 = H[(2 * tid) * NB + b];
    int v1 = H[(2 * tid + 1) * NB + b];
    lds[tid] = v0 + v1;
    __syncthreads();
    for (int off = 1; off < 256; off <<= 1) {
        int t = (tid >= off) ? lds[tid - off] : 0;
        __syncthreads();
        lds[tid] += t;
        __syncthreads();
    }
    int excl = (tid > 0) ? lds[tid - 1] : 0;
    H[(2 * tid) * NB + b] = excl;
    H[(2 * tid + 1) * NB + b] = excl + v0;
    if (tid == 255) btot[b] = excl + v0 + v1;
}

// ------- phase B2: exclusive scan of bucket totals -------
__global__ __launch_bounds__(256) void bucket_scan(const int* __restrict__ btot_d,
                                                   int* __restrict__ bbase_d,
                                                   const int* __restrict__ btot_s,
                                                   int* __restrict__ bbase_s) {
    __shared__ int lds[256];
    const int* in = (blockIdx.x == 0) ? btot_d : btot_s;
    int* out = (blockIdx.x == 0) ? bbase_d : bbase_s;
    int tid = threadIdx.x;
    int v[4]; int s = 0;
#pragma unroll
    for (int q = 0; q < 4; ++q) { v[q] = in[tid * 4 + q]; s += v[q]; }
    lds[tid] = s;
    __syncthreads();
    for (int off = 1; off < 256; off <<= 1) {
        int t = (tid >= off) ? lds[tid - off] : 0;
        __syncthreads();
        lds[tid] += t;
        __syncthreads();
    }
    int run = (tid > 0) ? lds[tid - 1] : 0;
#pragma unroll
    for (int q = 0; q < 4; ++q) { out[tid * 4 + q] = run; run += v[q]; }
    if (tid == 255) out[NB] = run;   // == N_EDGES
}

// ------- phase C: scatter edges into dst-buckets as (dst,src) pairs -------
__global__ __launch_bounds__(256) void scatter_dst(const int* __restrict__ src,
                                                   const int* __restrict__ dst,
                                                   const int* __restrict__ Hd,
                                                   const int* __restrict__ bbase_d,
                                                   int2* __restrict__ pedge) {
    __shared__ int cur[NB];
    int blk = blockIdx.x, tid = threadIdx.x;
    for (int i = tid; i < NB; i += 256) cur[i] = bbase_d[i] + Hd[blk * NB + i];
    __syncthreads();
    int e0 = blk * CHUNK, e1 = min(N_EDGES, e0 + CHUNK);
    for (int e = e0 + tid; e < e1; e += 256) {
        int d = dst[e], s = src[e];
        int pos = atomicAdd(&cur[d >> 10], 1);
        pedge[pos] = make_int2(d, s);
    }
}

// ------- phase C': scatter src values into src-buckets -------
__global__ __launch_bounds__(256) void scatter_src(const int* __restrict__ src,
                                                   const int* __restrict__ Hs,
                                                   const int* __restrict__ bbase_s,
                                                   int* __restrict__ psrc) {
    __shared__ int cur[NB];
    int blk = blockIdx.x, tid = threadIdx.x;
    for (int i = tid; i < NB; i += 256) cur[i] = bbase_s[i] + Hs[blk * NB + i];
    __syncthreads();
    int e0 = blk * CHUNK, e1 = min(N_EDGES, e0 + CHUNK);
    for (int e = e0 + tid; e < e1; e += 256) {
        int s = src[e];
        int pos = atomicAdd(&cur[s >> 10], 1);
        psrc[pos] = s;
    }
}

// ------- phase D1: per-bucket CSR build (LDS only) -------
__global__ __launch_bounds__(256) void bucket_csr(const int2* __restrict__ pedge,
                                                  const int* __restrict__ bbase_d,
                                                  int* __restrict__ eidx,
                                                  int* __restrict__ offs) {
    __shared__ int deg[NB];
    __shared__ int cur[NB];
    __shared__ int lds[256];
    int b = blockIdx.x, tid = threadIdx.x;
    int nbase = b << 10;
    if (nbase > N_ATOMS) return;
    int ebase = bbase_d[b], eend = bbase_d[b + 1];
    for (int i = tid; i < NB; i += 256) deg[i] = 0;
    __syncthreads();
    for (int i = ebase + tid; i < eend; i += 256)
        atomicAdd(&deg[pedge[i].x & (NB - 1)], 1);
    __syncthreads();
    int v[4]; int s = 0;
#pragma unroll
    for (int q = 0; q < 4; ++q) { v[q] = deg[tid * 4 + q]; s += v[q]; }
    lds[tid] = s;
    __syncthreads();
    for (int off = 1; off < 256; off <<= 1) {
        int t = (tid >= off) ? lds[tid - off] : 0;
        __syncthreads();
        lds[tid] += t;
        __syncthreads();
    }
    int run = (tid > 0) ? lds[tid - 1] : 0;
#pragma unroll
    for (int q = 0; q < 4; ++q) {
        int l = tid * 4 + q;
        cur[l] = run;
        int node = nbase + l;
        if (node <= N_ATOMS) offs[node] = ebase + run;
        run += v[q];
    }
    __syncthreads();
    for (int i = ebase + tid; i < eend; i += 256) {
        int2 ed = pedge[i];
        int p = atomicAdd(&cur[ed.x & (NB - 1)], 1);
        eidx[ebase + p] = ed.y;
    }
}

// ------- phase D2: per-bucket out-degree norm -------
__global__ __launch_bounds__(256) void bucket_ns(const int* __restrict__ psrc,
                                                 const int* __restrict__ bbase_s,
                                                 float* __restrict__ ns) {
    __shared__ int deg[NB];
    int b = blockIdx.x, tid = threadIdx.x;
    int nbase = b << 10;
    if (nbase >= N_ATOMS) return;
    int ebase = bbase_s[b], eend = bbase_s[b + 1];
    for (int i = tid; i < NB; i += 256) deg[i] = 0;
    __syncthreads();
    for (int i = ebase + tid; i < eend; i += 256)
        atomicAdd(&deg[psrc[i] & (NB - 1)], 1);
    __syncthreads();
    for (int l = tid; l < NB; l += 256) {
        int node = nbase + l;
        if (node < N_ATOMS) {
            int c = deg[l];
            ns[node] = c > 0 ? rsqrtf((float)c) : 0.0f;
        }
    }
}

// ------- input MLP: Linear(64->32) + LN + ELU, output prescaled by ns -> bf16 -------
__global__ __launch_bounds__(256) void input_mlp(const float* __restrict__ feats,
                                                 const float* __restrict__ w0,
                                                 const float* __restrict__ b0,
                                                 const float* __restrict__ g0,
                                                 const float* __restrict__ be0,
                                                 const float* __restrict__ ns,
                                                 ushort* __restrict__ hs) {
    __shared__ float sf[256 * 65];
    __shared__ float sw[IN_F * HID];
    int base = blockIdx.x * 256;
    int tid = threadIdx.x;

    for (int i = tid; i < IN_F * HID; i += 256) sw[i] = w0[i];

    int nrows = min(256, N_ATOMS - base);
    for (int i = tid; i < nrows * IN_F; i += 256) {
        int r = i >> 6, c = i & 63;
        sf[r * 65 + c] = feats[(size_t)base * IN_F + i];
    }
    __syncthreads();
    if (tid >= nrows) return;

    float acc[HID];
#pragma unroll
    for (int j = 0; j < HID; ++j) acc[j] = b0[j];

    const float* frow = &sf[tid * 65];
#pragma unroll 4
    for (int k = 0; k < IN_F; ++k) {
        float f = frow[k];
#pragma unroll
        for (int j = 0; j < HID; ++j) acc[j] += f * sw[k * HID + j];
    }

    float mu = 0.0f;
#pragma unroll
    for (int j = 0; j < HID; ++j) mu += acc[j];
    mu *= (1.0f / HID);
    float var = 0.0f;
#pragma unroll
    for (int j = 0; j < HID; ++j) { float d = acc[j] - mu; var += d * d; }
    var *= (1.0f / HID);
    float rs = rsqrtf(var + LN_EPS);

    float os = ns[base + tid];
#pragma unroll
    for (int j = 0; j < HID; ++j)
        acc[j] = elu_f((acc[j] - mu) * rs * g0[j] + be0[j]) * os;

    uint words[HID / 2];
#pragma unroll
    for (int q = 0; q < HID / 2; ++q)
        words[q] = f2bf(acc[2 * q]) | (f2bf(acc[2 * q + 1]) << 16);
    uint4* hv = (uint4*)&hs[(size_t)(base + tid) * HID];
#pragma unroll
    for (int q = 0; q < 4; ++q)
        hv[q] = make_uint4(words[4 * q], words[4 * q + 1], words[4 * q + 2], words[4 * q + 3]);
}

// ---- fused GraphConv + node MLP, 4 lanes per row ----
// Gather: each lane sums 8 features over all in-edges (4 edges in flight).
// MLP: distributed across the 4 lanes via LDS row exchange (stride-33,
// conflict-free); LN reduction via 4-lane shfl_xor. nd computed from offs.
__global__ __launch_bounds__(256) void conv4(const ushort* __restrict__ hin,
                                             const int* __restrict__ offs,
                                             const int* __restrict__ eidx,
                                             const float* __restrict__ wc,
                                             const float* __restrict__ bc,
                                             const float* __restrict__ w,
                                             const float* __restrict__ b,
                                             const float* __restrict__ g,
                                             const float* __restrict__ be,
                                             const float* __restrict__ ns_out,
                                             ushort* __restrict__ hout) {
    __shared__ float swc[HID * HID];
    __shared__ float sww[HID * HID];
    __shared__ float sm[64 * 33];
    int tid = threadIdx.x;
    for (int i = tid; i < HID * HID; i += 256) { swc[i] = wc[i]; sww[i] = w[i]; }

    int t = blockIdx.x * 256 + tid;        // grid covers exactly 4*N_ATOMS lanes
    int row = t >> 2;
    int l4 = (t & 3) * 8;                  // this lane's feature slice
    int lrow = tid >> 2;

    float a[8] = {0.f, 0.f, 0.f, 0.f, 0.f, 0.f, 0.f, 0.f};
    int s0 = offs[row], s1 = offs[row + 1];
    int i = s0;
    for (; i + 4 <= s1; i += 4) {
        int e0 = eidx[i], e1 = eidx[i + 1], e2 = eidx[i + 2], e3 = eidx[i + 3];
        uint4 r0 = *(const uint4*)(hin + (size_t)e0 * HID + l4);
        uint4 r1 = *(const uint4*)(hin + (size_t)e1 * HID + l4);
        uint4 r2 = *(const uint4*)(hin + (size_t)e2 * HID + l4);
        uint4 r3 = *(const uint4*)(hin + (size_t)e3 * HID + l4);
        acc8(a, r0); acc8(a, r1); acc8(a, r2); acc8(a, r3);
    }
    for (; i < s1; ++i) {
        uint4 r0 = *(const uint4*)(hin + (size_t)eidx[i] * HID + l4);
        acc8(a, r0);
    }

    float* myrow = &sm[lrow * 33];
#pragma unroll
    for (int jj = 0; jj < 8; ++jj) myrow[l4 + jj] = a[jj];
    __syncthreads();   // covers weights and sm

    int deg = s1 - s0;
    float scale = deg > 0 ? rsqrtf((float)deg) : 0.0f;

    // matmul1: t1[l4..l4+7] = (m*scale) @ wc + bc, then ELU
    float t1[8];
#pragma unroll
    for (int jj = 0; jj < 8; ++jj) t1[jj] = bc[l4 + jj];
    for (int k = 0; k < HID; ++k) {
        float f = myrow[k] * scale;
#pragma unroll
        for (int jj = 0; jj < 8; ++jj) t1[jj] += f * swc[k * HID + l4 + jj];
    }
#pragma unroll
    for (int jj = 0; jj < 8; ++jj) t1[jj] = elu_f(t1[jj]);

    // exchange t1 through the same LDS row; the 4 lanes of a row are in one
    // wave (lockstep, program-order DS ops) -> no barrier needed
#pragma unroll
    for (int jj = 0; jj < 8; ++jj) myrow[l4 + jj] = t1[jj];

    float t2[8];
#pragma unroll
    for (int jj = 0; jj < 8; ++jj) t2[jj] = b[l4 + jj];
    for (int k = 0; k < HID; ++k) {
        float f = myrow[k];
#pragma unroll
        for (int jj = 0; jj < 8; ++jj) t2[jj] += f * sww[k * HID + l4 + jj];
    }

    // LayerNorm across the 32-wide row: partial sums + 4-lane butterfly
    float s = 0.0f;
#pragma unroll
    for (int jj = 0; jj < 8; ++jj) s += t2[jj];
    s += __shfl_xor(s, 1);
    s += __shfl_xor(s, 2);
    float mu = s * (1.0f / HID);
    float v = 0.0f;
#pragma unroll
    for (int jj = 0; jj < 8; ++jj) { float d = t2[jj] - mu; v += d * d; }
    v += __shfl_xor(v, 1);
    v += __shfl_xor(v, 2);
    float rs = rsqrtf(v * (1.0f / HID) + LN_EPS);

    float os = ns_out ? ns_out[row] : 1.0f;
#pragma unroll
    for (int jj = 0; jj < 8; ++jj)
        t2[jj] = elu_f((t2[jj] - mu) * rs * g[l4 + jj] + be[l4 + jj]) * os;

    uint w0 = f2bf(t2[0]) | (f2bf(t2[1]) << 16);
    uint w1 = f2bf(t2[2]) | (f2bf(t2[3]) << 16);
    uint w2 = f2bf(t2[4]) | (f2bf(t2[5]) << 16);
    uint w3 = f2bf(t2[6]) | (f2bf(t2[7]) << 16);
    *(uint4*)(hout + (size_t)row * HID + l4) = make_uint4(w0, w1, w2, w3);
}

// ---------------- output head + per-graph readout (gid sorted) ----------------
__global__ __launch_bounds__(256) void readout(const ushort* __restrict__ h,
                                               const int* __restrict__ gid,
                                               const float* __restrict__ wout,
                                               const float* __restrict__ bout,
                                               float* __restrict__ out) {
    __shared__ float swout[HID];
    __shared__ float buckets[N_GRAPHS];
    __shared__ int s_gf, s_range;
    int base = blockIdx.x * 256;
    int tid = threadIdx.x;
    int nrows = min(256, N_ATOMS - base);

    if (tid < HID) swout[tid] = wout[tid];
    if (tid == 0) {
        int gf = gid[base];
        int gl = gid[base + nrows - 1];
        s_gf = gf;
        s_range = gl - gf + 1;
    }
    __syncthreads();
    int gf = s_gf, range = s_range;
    for (int i = tid; i < range; i += 256) buckets[i] = 0.0f;
    __syncthreads();

    if (tid < nrows) {
        int node = base + tid;
        const uint4* hv = (const uint4*)&h[(size_t)node * HID];
        float acc = bout[0];
#pragma unroll
        for (int q = 0; q < 4; ++q) {
            uint4 u = hv[q];
            uint vv[4] = {u.x, u.y, u.z, u.w};
#pragma unroll
            for (int r = 0; r < 4; ++r) {
                float lo = __uint_as_float(vv[r] << 16);
                float hi = __uint_as_float(vv[r] & 0xffff0000u);
                acc += lo * swout[q * 8 + r * 2] + hi * swout[q * 8 + r * 2 + 1];
            }
        }
        acc = elu_f(acc);
        atomicAdd(&buckets[gid[node] - gf], acc);
    }
    __syncthreads();
    for (int i = tid; i < range; i += 256) {
        float v = buckets[i];
        if (v != 0.0f) atomicAdd(&out[gf + i], v);
    }
}

extern "C" void kernel_launch(void* const* d_in, const int* in_sizes, int n_in,
                              void* d_out, int out_size, void* d_ws, size_t ws_size,
                              hipStream_t stream) {
    const float* feats = (const float*)d_in[0];
    const int* src = (const int*)d_in[1];
    const int* dst = (const int*)d_in[2];
    const int* gid = (const int*)d_in[3];
    const float* w0  = (const float*)d_in[4];
    const float* b0  = (const float*)d_in[5];
    const float* g0  = (const float*)d_in[6];
    const float* be0 = (const float*)d_in[7];
    const float* wc1 = (const float*)d_in[8];
    const float* bc1 = (const float*)d_in[9];
    const float* w1  = (const float*)d_in[10];
    const float* b1  = (const float*)d_in[11];
    const float* g1  = (const float*)d_in[12];
    const float* be1 = (const float*)d_in[13];
    const float* wc2 = (const float*)d_in[14];
    const float* bc2 = (const float*)d_in[15];
    const float* w2  = (const float*)d_in[16];
    const float* b2  = (const float*)d_in[17];
    const float* g2  = (const float*)d_in[18];
    const float* be2 = (const float*)d_in[19];
    const float* wout = (const float*)d_in[20];
    const float* bout = (const float*)d_in[21];
    float* out = (float*)d_out;

    // workspace layout — max offset 204,211,776 B (<= R4-proven 208 MB)
    char* ws = (char*)d_ws;
    ushort* h0    = (ushort*)(ws + 0);             // 64,000,000
    ushort* h1    = (ushort*)(ws + 64000000);      // 64,000,000
    int* offs     = (int*)(ws + 128000000);        // 4,000,064
    int* eidx     = (int*)(ws + 132000064);        // 16,000,000
    float* ns     = (float*)(ws + 148000064);      // 4,000,000
    // preprocessing scratch (dead after bucket_ns):
    int2* pedge   = (int2*)(ws + 152000064);       // 32,000,000
    int* psrc     = (int*)(ws + 184000064);        // 16,000,000
    int* Hd       = (int*)(ws + 200000064);        // 2,097,152
    int* Hs       = (int*)(ws + 202097216);        // 2,097,152
    int* btot_d   = (int*)(ws + 204194368);        // 4,096
    int* btot_s   = (int*)(ws + 204198464);        // 4,096
    int* bbase_d  = (int*)(ws + 204202560);        // 4,608
    int* bbase_s  = (int*)(ws + 204207168);        // 4,608

    hipMemsetAsync(out, 0, (size_t)N_GRAPHS * sizeof(float), stream);

    int nb = (N_ATOMS + 255) / 256;       // 3907
    int cb = (N_ATOMS * 4) / 256;         // 15625 (conv4 grid, exact)

    hist2<<<PB, 256, 0, stream>>>(src, dst, Hs, Hd);
    col_scan<<<NB, 256, 0, stream>>>(Hd, btot_d);
    col_scan<<<NB, 256, 0, stream>>>(Hs, btot_s);
    bucket_scan<<<2, 256, 0, stream>>>(btot_d, bbase_d, btot_s, bbase_s);
    scatter_dst<<<PB, 256, 0, stream>>>(src, dst, Hd, bbase_d, pedge);
    scatter_src<<<PB, 256, 0, stream>>>(src, Hs, bbase_s, psrc);
    bucket_csr<<<NBUCK_USED, 256, 0, stream>>>(pedge, bbase_d, eidx, offs);
    bucket_ns<<<NBUCK_USED, 256, 0, stream>>>(psrc, bbase_s, ns);

    input_mlp<<<nb, 256, 0, stream>>>(feats, w0, b0, g0, be0, ns, h0);

    conv4<<<cb, 256, 0, stream>>>(h0, offs, eidx, wc1, bc1, w1, b1, g1, be1, ns, h1);
    conv4<<<cb, 256, 0, stream>>>(h1, offs, eidx, wc2, bc2, w2, b2, g2, be2, nullptr, h0);

    readout<<<nb, 256, 0, stream>>>(h0, gid, wout, bout, out);
}

// Round 9
// 724.874 us; speedup vs baseline: 2.8067x; 1.9287x over previous
//
#include <hip/hip_runtime.h>
#include <math.h>

#define N_ATOMS 1000000
#define N_EDGES 4000000
#define N_GRAPHS 1024
#define IN_F 64
#define HID 32
#define LN_EPS 1e-5f
#define NB 1024                       // radix buckets (node_id >> 10)
#define PB 512                        // partition blocks
#define CHUNK ((N_EDGES + PB - 1) / PB)   // 7813
#define NBUCK_USED 977                // ceil(1e6 / 1024)

typedef unsigned int uint;
typedef unsigned short ushort;

__device__ __forceinline__ float elu_f(float x) {
    return x > 0.0f ? x : expm1f(x);
}
__device__ __forceinline__ uint f2bf(float x) {   // fp32 -> bf16 bits, RNE
    uint u = __float_as_uint(x);
    return (u + 0x7fffu + ((u >> 16) & 1u)) >> 16;
}
__device__ __forceinline__ void acc8(float* a, uint4 u) {
    uint v[4] = {u.x, u.y, u.z, u.w};
#pragma unroll
    for (int r = 0; r < 4; ++r) {
        a[2 * r]     += __uint_as_float(v[r] << 16);
        a[2 * r + 1] += __uint_as_float(v[r] & 0xffff0000u);
    }
}

// ------- phase A: per-block LDS histograms of src/dst buckets -------
__global__ __launch_bounds__(256) void hist2(const int* __restrict__ src,
                                             const int* __restrict__ dst,
                                             int* __restrict__ Hs,
                                             int* __restrict__ Hd) {
    __shared__ int hs[NB], hd[NB];
    int blk = blockIdx.x, tid = threadIdx.x;
    for (int i = tid; i < NB; i += 256) { hs[i] = 0; hd[i] = 0; }
    __syncthreads();
    int e0 = blk * CHUNK, e1 = min(N_EDGES, e0 + CHUNK);
    for (int e = e0 + tid; e < e1; e += 256) {
        atomicAdd(&hs[src[e] >> 10], 1);
        atomicAdd(&hd[dst[e] >> 10], 1);
    }
    __syncthreads();
    for (int i = tid; i < NB; i += 256) {
        Hs[blk * NB + i] = hs[i];
        Hd[blk * NB + i] = hd[i];
    }
}

// ------- phase B1: exclusive scan down each bucket column -------
__global__ __launch_bounds__(256) void col_scan(int* __restrict__ H,
                                                int* __restrict__ btot) {
    __shared__ int lds[256];
    int b = blockIdx.x, tid = threadIdx.x;
    int v0 = H[(2 * tid) * NB + b];
    int v1 = H[(2 * tid + 1) * NB + b];
    lds[tid] = v0 + v1;
    __syncthreads();
    for (int off = 1; off < 256; off <<= 1) {
        int t = (tid >= off) ? lds[tid - off] : 0;
        __syncthreads();
        lds[tid] += t;
        __syncthreads();
    }
    int excl = (tid > 0) ? lds[tid - 1] : 0;
    H[(2 * tid) * NB + b] = excl;
    H[(2 * tid + 1) * NB + b] = excl + v0;
    if (tid == 255) btot[b] = excl + v0 + v1;
}

// ------- phase B2: exclusive scan of bucket totals -------
__global__ __launch_bounds__(256) void bucket_scan(const int* __restrict__ btot_d,
                                                   int* __restrict__ bbase_d,
                                                   const int* __restrict__ btot_s,
                                                   int* __restrict__ bbase_s) {
    __shared__ int lds[256];
    const int* in = (blockIdx.x == 0) ? btot_d : btot_s;
    int* out = (blockIdx.x == 0) ? bbase_d : bbase_s;
    int tid = threadIdx.x;
    int v[4]; int s = 0;
#pragma unroll
    for (int q = 0; q < 4; ++q) { v[q] = in[tid * 4 + q]; s += v[q]; }
    lds[tid] = s;
    __syncthreads();
    for (int off = 1; off < 256; off <<= 1) {
        int t = (tid >= off) ? lds[tid - off] : 0;
        __syncthreads();
        lds[tid] += t;
        __syncthreads();
    }
    int run = (tid > 0) ? lds[tid - 1] : 0;
#pragma unroll
    for (int q = 0; q < 4; ++q) { out[tid * 4 + q] = run; run += v[q]; }
    if (tid == 255) out[NB] = run;   // == N_EDGES
}

// ------- phase C: scatter edges into dst-buckets as (dst,src) pairs -------
__global__ __launch_bounds__(256) void scatter_dst(const int* __restrict__ src,
                                                   const int* __restrict__ dst,
                                                   const int* __restrict__ Hd,
                                                   const int* __restrict__ bbase_d,
                                                   int2* __restrict__ pedge) {
    __shared__ int cur[NB];
    int blk = blockIdx.x, tid = threadIdx.x;
    for (int i = tid; i < NB; i += 256) cur[i] = bbase_d[i] + Hd[blk * NB + i];
    __syncthreads();
    int e0 = blk * CHUNK, e1 = min(N_EDGES, e0 + CHUNK);
    for (int e = e0 + tid; e < e1; e += 256) {
        int d = dst[e], s = src[e];
        int pos = atomicAdd(&cur[d >> 10], 1);
        pedge[pos] = make_int2(d, s);
    }
}

// ------- phase C': scatter src values into src-buckets -------
__global__ __launch_bounds__(256) void scatter_src(const int* __restrict__ src,
                                                   const int* __restrict__ Hs,
                                                   const int* __restrict__ bbase_s,
                                                   int* __restrict__ psrc) {
    __shared__ int cur[NB];
    int blk = blockIdx.x, tid = threadIdx.x;
    for (int i = tid; i < NB; i += 256) cur[i] = bbase_s[i] + Hs[blk * NB + i];
    __syncthreads();
    int e0 = blk * CHUNK, e1 = min(N_EDGES, e0 + CHUNK);
    for (int e = e0 + tid; e < e1; e += 256) {
        int s = src[e];
        int pos = atomicAdd(&cur[s >> 10], 1);
        psrc[pos] = s;
    }
}

// ------- phase D1: per-bucket CSR build (LDS only) -------
__global__ __launch_bounds__(256) void bucket_csr(const int2* __restrict__ pedge,
                                                  const int* __restrict__ bbase_d,
                                                  int* __restrict__ eidx,
                                                  int* __restrict__ offs) {
    __shared__ int deg[NB];
    __shared__ int cur[NB];
    __shared__ int lds[256];
    int b = blockIdx.x, tid = threadIdx.x;
    int nbase = b << 10;
    if (nbase > N_ATOMS) return;
    int ebase = bbase_d[b], eend = bbase_d[b + 1];
    for (int i = tid; i < NB; i += 256) deg[i] = 0;
    __syncthreads();
    for (int i = ebase + tid; i < eend; i += 256)
        atomicAdd(&deg[pedge[i].x & (NB - 1)], 1);
    __syncthreads();
    int v[4]; int s = 0;
#pragma unroll
    for (int q = 0; q < 4; ++q) { v[q] = deg[tid * 4 + q]; s += v[q]; }
    lds[tid] = s;
    __syncthreads();
    for (int off = 1; off < 256; off <<= 1) {
        int t = (tid >= off) ? lds[tid - off] : 0;
        __syncthreads();
        lds[tid] += t;
        __syncthreads();
    }
    int run = (tid > 0) ? lds[tid - 1] : 0;
#pragma unroll
    for (int q = 0; q < 4; ++q) {
        int l = tid * 4 + q;
        cur[l] = run;
        int node = nbase + l;
        if (node <= N_ATOMS) offs[node] = ebase + run;
        run += v[q];
    }
    __syncthreads();
    for (int i = ebase + tid; i < eend; i += 256) {
        int2 ed = pedge[i];
        int p = atomicAdd(&cur[ed.x & (NB - 1)], 1);
        eidx[ebase + p] = ed.y;
    }
}

// ------- phase D2: per-bucket out-degree norm -------
__global__ __launch_bounds__(256) void bucket_ns(const int* __restrict__ psrc,
                                                 const int* __restrict__ bbase_s,
                                                 float* __restrict__ ns) {
    __shared__ int deg[NB];
    int b = blockIdx.x, tid = threadIdx.x;
    int nbase = b << 10;
    if (nbase >= N_ATOMS) return;
    int ebase = bbase_s[b], eend = bbase_s[b + 1];
    for (int i = tid; i < NB; i += 256) deg[i] = 0;
    __syncthreads();
    for (int i = ebase + tid; i < eend; i += 256)
        atomicAdd(&deg[psrc[i] & (NB - 1)], 1);
    __syncthreads();
    for (int l = tid; l < NB; l += 256) {
        int node = nbase + l;
        if (node < N_ATOMS) {
            int c = deg[l];
            ns[node] = c > 0 ? rsqrtf((float)c) : 0.0f;
        }
    }
}

// ------- input MLP: Linear(64->32) + LN + ELU, output prescaled by ns -> bf16 -------
__global__ __launch_bounds__(256) void input_mlp(const float* __restrict__ feats,
                                                 const float* __restrict__ w0,
                                                 const float* __restrict__ b0,
                                                 const float* __restrict__ g0,
                                                 const float* __restrict__ be0,
                                                 const float* __restrict__ ns,
                                                 ushort* __restrict__ hs) {
    __shared__ float sf[256 * 65];
    __shared__ float sw[IN_F * HID];
    int base = blockIdx.x * 256;
    int tid = threadIdx.x;

    for (int i = tid; i < IN_F * HID; i += 256) sw[i] = w0[i];

    int nrows = min(256, N_ATOMS - base);
    for (int i = tid; i < nrows * IN_F; i += 256) {
        int r = i >> 6, c = i & 63;
        sf[r * 65 + c] = feats[(size_t)base * IN_F + i];
    }
    __syncthreads();
    if (tid >= nrows) return;

    float acc[HID];
#pragma unroll
    for (int j = 0; j < HID; ++j) acc[j] = b0[j];

    const float* frow = &sf[tid * 65];
#pragma unroll 4
    for (int k = 0; k < IN_F; ++k) {
        float f = frow[k];
#pragma unroll
        for (int j = 0; j < HID; ++j) acc[j] += f * sw[k * HID + j];
    }

    float mu = 0.0f;
#pragma unroll
    for (int j = 0; j < HID; ++j) mu += acc[j];
    mu *= (1.0f / HID);
    float var = 0.0f;
#pragma unroll
    for (int j = 0; j < HID; ++j) { float d = acc[j] - mu; var += d * d; }
    var *= (1.0f / HID);
    float rs = rsqrtf(var + LN_EPS);

    float os = ns[base + tid];
#pragma unroll
    for (int j = 0; j < HID; ++j)
        acc[j] = elu_f((acc[j] - mu) * rs * g0[j] + be0[j]) * os;

    uint words[HID / 2];
#pragma unroll
    for (int q = 0; q < HID / 2; ++q)
        words[q] = f2bf(acc[2 * q]) | (f2bf(acc[2 * q + 1]) << 16);
    uint4* hv = (uint4*)&hs[(size_t)(base + tid) * HID];
#pragma unroll
    for (int q = 0; q < 4; ++q)
        hv[q] = make_uint4(words[4 * q], words[4 * q + 1], words[4 * q + 2], words[4 * q + 3]);
}

// ------- SpMM gather: 4 lanes per row, 8 features each, 4 edges in flight -------
__global__ __launch_bounds__(256) void spmm4(const ushort* __restrict__ hin,
                                             const int* __restrict__ offs,
                                             const int* __restrict__ eidx,
                                             ushort* __restrict__ m) {
    int t = blockIdx.x * 256 + threadIdx.x;
    int row = t >> 2;
    int l4 = (t & 3) * 8;             // feature offset (in bf16 elems)
    int s0 = offs[row], s1 = offs[row + 1];

    float a[8] = {0.f, 0.f, 0.f, 0.f, 0.f, 0.f, 0.f, 0.f};
    int i = s0;
    for (; i + 4 <= s1; i += 4) {
        int e0 = eidx[i], e1 = eidx[i + 1], e2 = eidx[i + 2], e3 = eidx[i + 3];
        uint4 r0 = *(const uint4*)(hin + (size_t)e0 * HID + l4);
        uint4 r1 = *(const uint4*)(hin + (size_t)e1 * HID + l4);
        uint4 r2 = *(const uint4*)(hin + (size_t)e2 * HID + l4);
        uint4 r3 = *(const uint4*)(hin + (size_t)e3 * HID + l4);
        acc8(a, r0); acc8(a, r1); acc8(a, r2); acc8(a, r3);
    }
    for (; i < s1; ++i) {
        uint4 r0 = *(const uint4*)(hin + (size_t)eidx[i] * HID + l4);
        acc8(a, r0);
    }

    uint w0 = f2bf(a[0]) | (f2bf(a[1]) << 16);
    uint w1 = f2bf(a[2]) | (f2bf(a[3]) << 16);
    uint w2 = f2bf(a[4]) | (f2bf(a[5]) << 16);
    uint w3 = f2bf(a[6]) | (f2bf(a[7]) << 16);
    *(uint4*)(m + (size_t)row * HID + l4) = make_uint4(w0, w1, w2, w3);
}

// ------- streaming node MLP: nd*m @ wc -> ELU -> @ w -> LN -> ELU (* ns) -> bf16 -------
// nd recomputed from offs (in-degree). FIX vs R6/R8: read the FULL 64-byte row
// (4 x uint4 -> 32 floats); previous version read only half, leaving
// acc[16..31] uninitialized.
__global__ __launch_bounds__(256) void mlp_node(const ushort* __restrict__ m,
                                                const int* __restrict__ offs,
                                                const float* __restrict__ wc,
                                                const float* __restrict__ bc,
                                                const float* __restrict__ w,
                                                const float* __restrict__ b,
                                                const float* __restrict__ g,
                                                const float* __restrict__ be,
                                                const float* __restrict__ ns_out,
                                                ushort* __restrict__ hout) {
    __shared__ float swc[HID * HID];
    __shared__ float sww[HID * HID];
    int tid = threadIdx.x;
    for (int i = tid; i < HID * HID; i += 256) { swc[i] = wc[i]; sww[i] = w[i]; }
    __syncthreads();

    int node = blockIdx.x * 256 + tid;
    if (node >= N_ATOMS) return;

    int deg = offs[node + 1] - offs[node];
    float scale = deg > 0 ? rsqrtf((float)deg) : 0.0f;

    const uint4* mr = (const uint4*)(m + (size_t)node * HID);
    uint4 u0 = mr[0], u1 = mr[1], u2 = mr[2], u3 = mr[3];
    float acc[HID];
    {
        uint vv[16] = {u0.x, u0.y, u0.z, u0.w, u1.x, u1.y, u1.z, u1.w,
                       u2.x, u2.y, u2.z, u2.w, u3.x, u3.y, u3.z, u3.w};
#pragma unroll
        for (int r = 0; r < 16; ++r) {
            acc[2 * r]     = __uint_as_float(vv[r] << 16) * scale;
            acc[2 * r + 1] = __uint_as_float(vv[r] & 0xffff0000u) * scale;
        }
    }

    float t1[HID];
#pragma unroll
    for (int j = 0; j < HID; ++j) t1[j] = bc[j];
#pragma unroll 4
    for (int k = 0; k < HID; ++k) {
        float f = acc[k];
#pragma unroll
        for (int j = 0; j < HID; ++j) t1[j] += f * swc[k * HID + j];
    }
#pragma unroll
    for (int j = 0; j < HID; ++j) t1[j] = elu_f(t1[j]);

    float t2[HID];
#pragma unroll
    for (int j = 0; j < HID; ++j) t2[j] = b[j];
#pragma unroll 4
    for (int k = 0; k < HID; ++k) {
        float f = t1[k];
#pragma unroll
        for (int j = 0; j < HID; ++j) t2[j] += f * sww[k * HID + j];
    }

    float mu = 0.0f;
#pragma unroll
    for (int j = 0; j < HID; ++j) mu += t2[j];
    mu *= (1.0f / HID);
    float var = 0.0f;
#pragma unroll
    for (int j = 0; j < HID; ++j) { float d = t2[j] - mu; var += d * d; }
    var *= (1.0f / HID);
    float rs = rsqrtf(var + LN_EPS);

    float os = ns_out ? ns_out[node] : 1.0f;
#pragma unroll
    for (int j = 0; j < HID; ++j)
        t2[j] = elu_f((t2[j] - mu) * rs * g[j] + be[j]) * os;

    uint words[HID / 2];
#pragma unroll
    for (int q = 0; q < HID / 2; ++q)
        words[q] = f2bf(t2[2 * q]) | (f2bf(t2[2 * q + 1]) << 16);
    uint4* hv = (uint4*)&hout[(size_t)node * HID];
#pragma unroll
    for (int q = 0; q < 4; ++q)
        hv[q] = make_uint4(words[4 * q], words[4 * q + 1], words[4 * q + 2], words[4 * q + 3]);
}

// ---------------- output head + per-graph readout (gid sorted) ----------------
__global__ __launch_bounds__(256) void readout(const ushort* __restrict__ h,
                                               const int* __restrict__ gid,
                                               const float* __restrict__ wout,
                                               const float* __restrict__ bout,
                                               float* __restrict__ out) {
    __shared__ float swout[HID];
    __shared__ float buckets[N_GRAPHS];
    __shared__ int s_gf, s_range;
    int base = blockIdx.x * 256;
    int tid = threadIdx.x;
    int nrows = min(256, N_ATOMS - base);

    if (tid < HID) swout[tid] = wout[tid];
    if (tid == 0) {
        int gf = gid[base];
        int gl = gid[base + nrows - 1];
        s_gf = gf;
        s_range = gl - gf + 1;
    }
    __syncthreads();
    int gf = s_gf, range = s_range;
    for (int i = tid; i < range; i += 256) buckets[i] = 0.0f;
    __syncthreads();

    if (tid < nrows) {
        int node = base + tid;
        const uint4* hv = (const uint4*)&h[(size_t)node * HID];
        float acc = bout[0];
#pragma unroll
        for (int q = 0; q < 4; ++q) {
            uint4 u = hv[q];
            uint vv[4] = {u.x, u.y, u.z, u.w};
#pragma unroll
            for (int r = 0; r < 4; ++r) {
                float lo = __uint_as_float(vv[r] << 16);
                float hi = __uint_as_float(vv[r] & 0xffff0000u);
                acc += lo * swout[q * 8 + r * 2] + hi * swout[q * 8 + r * 2 + 1];
            }
        }
        acc = elu_f(acc);
        atomicAdd(&buckets[gid[node] - gf], acc);
    }
    __syncthreads();
    for (int i = tid; i < range; i += 256) {
        float v = buckets[i];
        if (v != 0.0f) atomicAdd(&out[gf + i], v);
    }
}

extern "C" void kernel_launch(void* const* d_in, const int* in_sizes, int n_in,
                              void* d_out, int out_size, void* d_ws, size_t ws_size,
                              hipStream_t stream) {
    const float* feats = (const float*)d_in[0];
    const int* src = (const int*)d_in[1];
    const int* dst = (const int*)d_in[2];
    const int* gid = (const int*)d_in[3];
    const float* w0  = (const float*)d_in[4];
    const float* b0  = (const float*)d_in[5];
    const float* g0  = (const float*)d_in[6];
    const float* be0 = (const float*)d_in[7];
    const float* wc1 = (const float*)d_in[8];
    const float* bc1 = (const float*)d_in[9];
    const float* w1  = (const float*)d_in[10];
    const float* b1  = (const float*)d_in[11];
    const float* g1  = (const float*)d_in[12];
    const float* be1 = (const float*)d_in[13];
    const float* wc2 = (const float*)d_in[14];
    const float* bc2 = (const float*)d_in[15];
    const float* w2  = (const float*)d_in[16];
    const float* b2  = (const float*)d_in[17];
    const float* g2  = (const float*)d_in[18];
    const float* be2 = (const float*)d_in[19];
    const float* wout = (const float*)d_in[20];
    const float* bout = (const float*)d_in[21];
    float* out = (float*)d_out;

    // workspace layout — max offset 204,211,776 B (== R7-proven footprint)
    char* ws = (char*)d_ws;
    ushort* X     = (ushort*)(ws + 0);             // 64,000,000  (h buffer)
    ushort* M     = (ushort*)(ws + 64000000);      // 64,000,000  (gathered sums)
    int* offs     = (int*)(ws + 128000000);        // 4,000,064
    int* eidx     = (int*)(ws + 132000064);        // 16,000,000
    float* ns     = (float*)(ws + 148000064);      // 4,000,000
    // preprocessing scratch (dead after bucket_ns):
    int2* pedge   = (int2*)(ws + 152000064);       // 32,000,000
    int* psrc     = (int*)(ws + 184000064);        // 16,000,000
    int* Hd       = (int*)(ws + 200000064);        // 2,097,152
    int* Hs       = (int*)(ws + 202097216);        // 2,097,152
    int* btot_d   = (int*)(ws + 204194368);        // 4,096
    int* btot_s   = (int*)(ws + 204198464);        // 4,096
    int* bbase_d  = (int*)(ws + 204202560);        // 4,608
    int* bbase_s  = (int*)(ws + 204207168);        // 4,608

    hipMemsetAsync(out, 0, (size_t)N_GRAPHS * sizeof(float), stream);

    int nb = (N_ATOMS + 255) / 256;       // 3907
    int sb = (N_ATOMS * 4) / 256;         // 15625 (spmm4 grid, exact)

    hist2<<<PB, 256, 0, stream>>>(src, dst, Hs, Hd);
    col_scan<<<NB, 256, 0, stream>>>(Hd, btot_d);
    col_scan<<<NB, 256, 0, stream>>>(Hs, btot_s);
    bucket_scan<<<2, 256, 0, stream>>>(btot_d, bbase_d, btot_s, bbase_s);
    scatter_dst<<<PB, 256, 0, stream>>>(src, dst, Hd, bbase_d, pedge);
    scatter_src<<<PB, 256, 0, stream>>>(src, Hs, bbase_s, psrc);
    bucket_csr<<<NBUCK_USED, 256, 0, stream>>>(pedge, bbase_d, eidx, offs);
    bucket_ns<<<NBUCK_USED, 256, 0, stream>>>(psrc, bbase_s, ns);

    input_mlp<<<nb, 256, 0, stream>>>(feats, w0, b0, g0, be0, ns, X);

    // conv block 1
    spmm4<<<sb, 256, 0, stream>>>(X, offs, eidx, M);
    mlp_node<<<nb, 256, 0, stream>>>(M, offs, wc1, bc1, w1, b1, g1, be1, ns, X);
    // conv block 2
    spmm4<<<sb, 256, 0, stream>>>(X, offs, eidx, M);
    mlp_node<<<nb, 256, 0, stream>>>(M, offs, wc2, bc2, w2, b2, g2, be2, nullptr, X);

    readout<<<nb, 256, 0, stream>>>(X, gid, wout, bout, out);
}